// Round 6
// baseline (553.346 us; speedup 1.0000x reference)
//
#include <hip/hip_runtime.h>
#include <hip/hip_bf16.h>
#include <cstdint>
#include <cstddef>

#define SEQ_ 2048

typedef __bf16 v8bf __attribute__((ext_vector_type(8)));
typedef float v4f __attribute__((ext_vector_type(4)));

__device__ __forceinline__ unsigned short f2bf(float f) {
  unsigned u = __float_as_uint(f);
  return (unsigned short)((u + 0x7FFFu + ((u >> 16) & 1u)) >> 16);
}
__device__ __forceinline__ float bf2f(unsigned short h) {
  return __uint_as_float(((unsigned)h) << 16);
}
__device__ __forceinline__ float silu_(float x) { return x / (1.f + expf(-x)); }
__device__ __forceinline__ float gelu_(float x) { return 0.5f * x * (1.f + erff(x * 0.70710678118654752f)); }

__device__ __forceinline__ void gl_lds16(const void* g, void* l) {
  __builtin_amdgcn_global_load_lds((const __attribute__((address_space(1))) void*)g,
                                   (__attribute__((address_space(3))) void*)l, 16, 0, 0);
}

// stage ROWS x 64 bf16 (128B rows), source row stride ldk elements, XOR-swizzled
template <int ROWS>
__device__ __forceinline__ void stage_t(const unsigned short* gsrc, int ldk, char* lds, int tid) {
  const int wid = tid >> 6;
#pragma unroll
  for (int p = 0; p < ROWS / 32; ++p) {
    const int L = p * 256 + tid;
    const int row = L >> 3, slot = L & 7;
    gl_lds16((const char*)(gsrc + (size_t)row * ldk) + ((slot * 16) ^ ((row & 7) << 4)),
             lds + (p * 256 + wid * 64) * 16);
  }
}

// stage NROWS x 256B rows (row byte-stride srow), XOR-swizzled
template <int NROWS>
__device__ __forceinline__ void stage_rows(const char* gbase, int srow, char* lds, int tid) {
  const int wid = tid >> 6;
#pragma unroll
  for (int q = 0; q < NROWS / 16; ++q) {
    const int L = q * 256 + tid;
    const int row = L >> 4;
    const int slot = L & 15;
    gl_lds16(gbase + (size_t)row * srow + ((slot * 16) ^ ((row & 7) << 4)),
             lds + (q * 256 + wid * 64) * 16);
  }
}

// ---------------- fused setup: xpos tables + coalesced tiled weight transposes ----------------
__global__ __launch_bounds__(256) void setup_k(const float* __restrict__ Wq, const float* __restrict__ Wk,
                                               const float* __restrict__ Wv, const float* __restrict__ Wg,
                                               const float* __restrict__ Wo, const float* __restrict__ f1w,
                                               const float* __restrict__ f2w, float* __restrict__ tab,
                                               unsigned short* __restrict__ WTQ, unsigned short* __restrict__ WTO,
                                               unsigned short* __restrict__ WF1, unsigned short* __restrict__ WF2) {
  const int b = blockIdx.x, tid = threadIdx.x;
  if (b < 512) {
    const int idx = b * 256 + tid;
    const int pos = idx >> 6, i = idx & 63;
    const float si = (2.f * (float)i + 51.2f) * (1.f / 179.2f);
    const float sc = powf(si, (float)pos * (1.f / 512.f));
    const float invf = powf(10000.f, -(float)i * (1.f / 64.f));
    const float ang = (float)pos * invf;
    const float cs = cosf(ang), sn = sinf(ang);
    tab[idx] = cs * sc;
    tab[131072 + idx] = sn * sc;
    tab[262144 + idx] = cs / sc;
    tab[393216 + idx] = sn / sc;
    return;
  }
  __shared__ float t[64][65];
  const float* src;
  unsigned short* dst;
  int ldn, ldk;
  int b2 = b - 512;
  if (b2 < 768) {  // Q/K/V: [l][h][512][128] -> WTQ [l][sec*512+h*128+e][512]
    const int l = b2 / 192, r = b2 % 192, sec = r / 64, r2 = r % 64, h = r2 >> 4, tt = r2 & 15;
    const int kt = tt >> 1, et = tt & 1;
    const float* W = (sec == 0) ? Wq : (sec == 1) ? Wk : Wv;
    src = W + (((size_t)(l * 4 + h) * 512 + kt * 64) * 128 + et * 64);
    ldn = 128;
    dst = WTQ + (size_t)l * 1048576 + (size_t)(sec * 512 + h * 128 + et * 64) * 512 + kt * 64;
    ldk = 512;
  } else if (b2 < 1024) {  // Wg: [l][512][512] -> WTQ cols 1536..2047
    b2 -= 768;
    const int l = b2 >> 6, tt = b2 & 63, kt = tt >> 3, nt = tt & 7;
    src = Wg + (size_t)l * 262144 + (size_t)kt * 64 * 512 + nt * 64;
    ldn = 512;
    dst = WTQ + (size_t)l * 1048576 + (size_t)(1536 + nt * 64) * 512 + kt * 64;
    ldk = 512;
  } else if (b2 < 1280) {  // Wo
    b2 -= 1024;
    const int l = b2 >> 6, tt = b2 & 63, kt = tt >> 3, nt = tt & 7;
    src = Wo + (size_t)l * 262144 + (size_t)kt * 64 * 512 + nt * 64;
    ldn = 512;
    dst = WTO + (size_t)l * 262144 + (size_t)nt * 64 * 512 + kt * 64;
    ldk = 512;
  } else if (b2 < 1792) {  // f1: [l][512][1024] -> [l][1024][512]
    b2 -= 1280;
    const int l = b2 >> 7, tt = b2 & 127, kt = tt >> 4, nt = tt & 15;
    src = f1w + (size_t)l * 524288 + (size_t)kt * 64 * 1024 + nt * 64;
    ldn = 1024;
    dst = WF1 + (size_t)l * 524288 + (size_t)nt * 64 * 512 + kt * 64;
    ldk = 512;
  } else {  // f2: [l][1024][512] -> [l][512][1024]
    b2 -= 1792;
    const int l = b2 >> 7, tt = b2 & 127, kt = tt >> 3, nt = tt & 7;
    src = f2w + (size_t)l * 524288 + (size_t)kt * 64 * 512 + nt * 64;
    ldn = 512;
    dst = WF2 + (size_t)l * 524288 + (size_t)nt * 64 * 1024 + kt * 64;
    ldk = 1024;
  }
#pragma unroll
  for (int p = 0; p < 4; ++p) {
    const int idx = p * 256 + tid;
    const int kr = idx >> 4, c4 = (idx & 15) * 4;
    const float4 v = *(const float4*)(src + (size_t)kr * ldn + c4);
    t[kr][c4] = v.x; t[kr][c4 + 1] = v.y; t[kr][c4 + 2] = v.z; t[kr][c4 + 3] = v.w;
  }
  __syncthreads();
#pragma unroll
  for (int p = 0; p < 2; ++p) {
    const int idx = p * 256 + tid;
    const int nr = idx >> 3, k8 = (idx & 7) * 8;
    unsigned short o[8];
#pragma unroll
    for (int j = 0; j < 8; ++j) o[j] = f2bf(t[k8 + j][nr]);
    uint4 pk;
    pk.x = o[0] | ((unsigned)o[1] << 16);
    pk.y = o[2] | ((unsigned)o[3] << 16);
    pk.z = o[4] | ((unsigned)o[5] << 16);
    pk.w = o[6] | ((unsigned)o[7] << 16);
    *(uint4*)(dst + (size_t)nr * ldk + k8) = pk;
  }
}

// ---------------- LayerNorm (fp32 in, bf16 out) ----------------
__global__ __launch_bounds__(256) void ln_bf_k(const float* __restrict__ x, const float* __restrict__ w,
                                               const float* __restrict__ bv, unsigned short* __restrict__ out) {
  const int row = blockIdx.x * 4 + (threadIdx.x >> 6);
  const int lane = threadIdx.x & 63;
  const float* xr = x + (size_t)row * 512 + lane * 8;
  const float4 v0 = *(const float4*)xr;
  const float4 v1 = *(const float4*)(xr + 4);
  float va[8] = {v0.x, v0.y, v0.z, v0.w, v1.x, v1.y, v1.z, v1.w};
  float s = 0.f, ss = 0.f;
#pragma unroll
  for (int j = 0; j < 8; ++j) { s += va[j]; ss += va[j] * va[j]; }
#pragma unroll
  for (int o = 1; o < 64; o <<= 1) { s += __shfl_xor(s, o); ss += __shfl_xor(ss, o); }
  const float mu = s * (1.f / 512.f);
  const float var = ss * (1.f / 512.f) - mu * mu;
  const float rstd = rsqrtf(var + 1e-5f);
  const int c = lane * 8;
  unsigned short o16[8];
#pragma unroll
  for (int j = 0; j < 8; ++j) o16[j] = f2bf((va[j] - mu) * rstd * w[c + j] + bv[c + j]);
  uint4 pk;
  pk.x = o16[0] | ((unsigned)o16[1] << 16);
  pk.y = o16[2] | ((unsigned)o16[3] << 16);
  pk.z = o16[4] | ((unsigned)o16[5] << 16);
  pk.w = o16[6] | ((unsigned)o16[7] << 16);
  *(uint4*)(out + (size_t)row * 512 + c) = pk;
}

// ---------------- bf16 MFMA GEMM: BK=64, double-buffered 1-deep prefetch ----------------
template <int BM, int BN, int EPI>
__global__ __launch_bounds__(256) void mm_k(
    const unsigned short* __restrict__ A, const unsigned short* __restrict__ Bt, const int K,
    const float* __restrict__ t_qc, const float* __restrict__ t_qs,
    const float* __restrict__ t_kc, const float* __restrict__ t_ks,
    unsigned short* __restrict__ o_q, unsigned short* __restrict__ o_k,
    unsigned short* __restrict__ o_ktw, unsigned short* __restrict__ o_vt,
    unsigned short* __restrict__ o_g0,
    const float* __restrict__ auxf, const float* __restrict__ auxf2,
    float* __restrict__ o_f32, unsigned short* __restrict__ o_bf16) {
  constexpr int MR = BM / 32, NR = BN / 32;
  constexpr int BMB = BM * 128, BNB = BN * 128;
  __shared__ __align__(16) char smem[2 * (BMB + BNB)];
  const int tid = threadIdx.x, lane = tid & 63, wid = tid >> 6;
  const int wr = wid >> 1, wc = wid & 1;
  const int l15 = lane & 15, l4 = lane >> 4;
  const int m0 = blockIdx.x * BM, n0 = blockIdx.y * BN;
  const int N = gridDim.y * BN;
  v4f acc[MR][NR];
#pragma unroll
  for (int i = 0; i < MR; ++i)
#pragma unroll
    for (int j = 0; j < NR; ++j) acc[i][j] = v4f{0.f, 0.f, 0.f, 0.f};

  const unsigned short* Ab = A + (size_t)m0 * K;
  const unsigned short* Bb = Bt + (size_t)n0 * K;
  const int NT = K >> 6;
  int cur = 0;
  stage_t<BM>(Ab, K, smem, tid);
  stage_t<BN>(Bb, K, smem + 2 * BMB, tid);
  __syncthreads();
  for (int t = 0; t < NT; ++t) {
    if (t + 1 < NT) {
      stage_t<BM>(Ab + (t + 1) * 64, K, smem + (cur ^ 1) * BMB, tid);
      stage_t<BN>(Bb + (t + 1) * 64, K, smem + 2 * BMB + (cur ^ 1) * BNB, tid);
    }
    const char* Ac = smem + cur * BMB;
    const char* Bc = smem + 2 * BMB + cur * BNB;
#pragma unroll
    for (int ks = 0; ks < 2; ++ks) {
      v8bf af[MR], bfv[NR];
#pragma unroll
      for (int i = 0; i < MR; ++i) {
        const int row = wr * (BM / 2) + i * 16 + l15;
        af[i] = *(const v8bf*)(Ac + row * 128 + ((ks * 64 + l4 * 16) ^ ((row & 7) << 4)));
      }
#pragma unroll
      for (int j = 0; j < NR; ++j) {
        const int row = wc * (BN / 2) + j * 16 + l15;
        bfv[j] = *(const v8bf*)(Bc + row * 128 + ((ks * 64 + l4 * 16) ^ ((row & 7) << 4)));
      }
#pragma unroll
      for (int i = 0; i < MR; ++i)
#pragma unroll
        for (int j = 0; j < NR; ++j)
          acc[i][j] = __builtin_amdgcn_mfma_f32_16x16x32_bf16(af[i], bfv[j], acc[i][j], 0, 0, 0);
    }
    __syncthreads();
    cur ^= 1;
  }

  // ---- epilogue ----
  if constexpr (EPI == 0) {
    const int sec = n0 >> 9;
    const int h = (n0 >> 7) & 3;
    const int srow0 = m0 & (SEQ_ - 1);
    const int bh = ((m0 >> 11) << 2) | h;
    unsigned short* sT = (unsigned short*)smem;  // [128 e][136]
    const float gamma = 1.f - expf(-3.4657359028f - 0.9241962407f * (float)h);
    const float l2g = log2f(gamma);
#pragma unroll
    for (int i = 0; i < MR; ++i) {
#pragma unroll
      for (int r = 0; r < 4; ++r) {
        const int rl = wr * (BM / 2) + i * 16 + l4 * 4 + r;
        const int srow = srow0 + rl;
        const float wk = (sec == 1) ? exp2f(l2g * (float)(127 - (rl & 127))) : 0.f;
#pragma unroll
        for (int j = 0; j < NR; ++j) {
          const int cl = wc * (BN / 2) + j * 16 + l15;
          float v = acc[i][j][r];
          if (sec <= 1) {
            const float p = __shfl_xor(v, 1);
            const float* ct = (sec == 0) ? t_qc : t_kc;
            const float* st = (sec == 0) ? t_qs : t_ks;
            const float c_ = ct[srow * 64 + (cl >> 1)];
            const float s_ = st[srow * 64 + (cl >> 1)];
            const float o = (lane & 1) ? fmaf(v, c_, p * s_) : fmaf(v, c_, -p * s_);
            if (sec == 0) {
              o_q[((size_t)bh * SEQ_ + srow) * 128 + cl] = f2bf(o);
            } else {
              o_k[((size_t)bh * SEQ_ + srow) * 128 + cl] = f2bf(o);
              sT[cl * 136 + rl] = f2bf(o * wk);
            }
          } else if (sec == 2) {
            sT[cl * 136 + rl] = f2bf(v);
          } else {
            o_g0[(size_t)(m0 + rl) * 512 + cl] = f2bf(v);
          }
        }
      }
    }
    if (sec == 1 || sec == 2) {
      __syncthreads();
      unsigned short* dstT = ((sec == 1) ? o_ktw : o_vt) + (size_t)bh * 128 * SEQ_ + srow0;
#pragma unroll
      for (int u = 0; u < 8; ++u) {
        const int idx = u * 256 + tid;
        const int d = idx >> 4, j8 = idx & 15;
        *(v8bf*)(dstT + (size_t)d * SEQ_ + j8 * 8) = *(const v8bf*)(sT + d * 136 + j8 * 8);
      }
    }
  } else {
#pragma unroll
    for (int i = 0; i < MR; ++i) {
#pragma unroll
      for (int r = 0; r < 4; ++r) {
        const int row = m0 + wr * (BM / 2) + i * 16 + l4 * 4 + r;
#pragma unroll
        for (int j = 0; j < NR; ++j) {
          const int col = n0 + wc * (BN / 2) + j * 16 + l15;
          const float v = acc[i][j][r];
          if constexpr (EPI == 1) {
            o_f32[(size_t)row * 512 + col] = v + auxf[(size_t)row * 512 + col];
          } else if constexpr (EPI == 2) {
            o_bf16[(size_t)row * N + col] = f2bf(gelu_(v + auxf[col]));
          } else {
            o_f32[(size_t)row * 512 + col] = v + auxf[col] + auxf2[(size_t)row * 512 + col];
          }
        }
      }
    }
  }
}

// ---------------- fused retention phase 1+2: chunk summaries + in-register decay scan ----------------
// grid (8 bh, 4 e-slices of 32). Per chunk: U_c[e][d] = sum_i V[i][e] Kw[i][d]; write S_c; state = state*g128 + U_c.
__global__ __launch_bounds__(256) void ret12_k(const unsigned short* __restrict__ VT,
                                               const unsigned short* __restrict__ KTw,
                                               unsigned short* __restrict__ Sb) {
  __shared__ __align__(16) char lV[8192];   // 32 e-rows x 256B
  __shared__ __align__(16) char lK[32768];  // 128 d-rows x 256B
  const int bh = blockIdx.x, es = blockIdx.y * 32;
  const int tid = threadIdx.x, lane = tid & 63, wid = tid >> 6;
  const int wr = wid >> 1, wc = wid & 1;
  const int l15 = lane & 15, l4 = lane >> 4;
  const int h = bh & 3;
  const float gamma = 1.f - expf(-3.4657359028f - 0.9241962407f * (float)h);
  const float g128 = exp2f(log2f(gamma) * 128.f);
  const char* Vbase = (const char*)(VT + ((size_t)bh * 128 + es) * SEQ_);
  const char* Kbase = (const char*)(KTw + (size_t)bh * 128 * SEQ_);
  v4f st[4];
#pragma unroll
  for (int j = 0; j < 4; ++j) st[j] = v4f{0.f, 0.f, 0.f, 0.f};
  for (int c = 0; c < 16; ++c) {
    stage_rows<32>(Vbase + (size_t)c * 256, SEQ_ * 2, lV, tid);
    stage_rows<128>(Kbase + (size_t)c * 256, SEQ_ * 2, lK, tid);
    __syncthreads();
    v4f u[4];
#pragma unroll
    for (int j = 0; j < 4; ++j) u[j] = v4f{0.f, 0.f, 0.f, 0.f};
#pragma unroll
    for (int ks = 0; ks < 4; ++ks) {
      const int ra = wr * 16 + l15;
      const v8bf af = *(const v8bf*)(lV + ra * 256 + ((ks * 64 + l4 * 16) ^ ((ra & 7) << 4)));
      v8bf bfv[4];
#pragma unroll
      for (int j = 0; j < 4; ++j) {
        const int rb = wc * 64 + j * 16 + l15;
        bfv[j] = *(const v8bf*)(lK + rb * 256 + ((ks * 64 + l4 * 16) ^ ((rb & 7) << 4)));
      }
#pragma unroll
      for (int j = 0; j < 4; ++j)
        u[j] = __builtin_amdgcn_mfma_f32_16x16x32_bf16(af, bfv[j], u[j], 0, 0, 0);
    }
    // write current state (pre-add) as S_c, then update state
    unsigned short* sc = Sb + ((size_t)bh * 16 + c) * 16384;
#pragma unroll
    for (int r = 0; r < 4; ++r) {
      const int e = es + wr * 16 + l4 * 4 + r;
#pragma unroll
      for (int j = 0; j < 4; ++j) {
        const int d = wc * 64 + j * 16 + l15;
        sc[e * 128 + d] = f2bf(st[j][r]);
        st[j][r] = st[j][r] * g128 + u[j][r];
      }
    }
    __syncthreads();  // all reads of lV/lK done before next stage
  }
}

// ---------------- retention phase 3: half-chunk blocks, output + groupnorm + gate ----------------
template <int HF>
__device__ __forceinline__ void ret3_body(
    const unsigned short* Qb, const unsigned short* Kb, const unsigned short* VTb,
    const unsigned short* Sb, const unsigned short* G0b, const float* gnw,
    const float* gnb, unsigned short* Gb, char* lA, char* lB, const float* dpw,
    float* rs, int bh, int c, int tid) {
  const int h = bh & 3, b = bh >> 2;
  const int lane = tid & 63, wid = tid >> 6;
  const int wr = wid >> 1, wc = wid & 1;
  const int l15 = lane & 15, l4 = lane >> 4;
  constexpr int NS = 2 + 2 * HF;     // QK col frags per wave
  constexpr int KS = 2 + 2 * HF;     // PV k-steps
  const int j0 = c * 128 + HF * 64;  // global chunk-row base

  // stage Q (64x256B) -> lA, S (128x256B) -> lB
  stage_rows<64>((const char*)(Qb + ((size_t)bh * SEQ_ + j0) * 128), 256, lA, tid);
  stage_rows<128>((const char*)(Sb + ((size_t)bh * 16 + c) * 16384), 256, lB, tid);
  __syncthreads();

  // inter-chunk: O = Q @ S_before  (out 64 x 128)
  v4f acc[2][4];
#pragma unroll
  for (int i = 0; i < 2; ++i)
#pragma unroll
    for (int j = 0; j < 4; ++j) acc[i][j] = v4f{0.f, 0.f, 0.f, 0.f};
#pragma unroll
  for (int ks = 0; ks < 4; ++ks) {
    v8bf af[2], bfv[4];
#pragma unroll
    for (int i = 0; i < 2; ++i) {
      const int ra = wr * 32 + i * 16 + l15;
      af[i] = *(const v8bf*)(lA + ra * 256 + ((ks * 64 + l4 * 16) ^ ((ra & 7) << 4)));
    }
#pragma unroll
    for (int j = 0; j < 4; ++j) {
      const int rb = wc * 64 + j * 16 + l15;
      bfv[j] = *(const v8bf*)(lB + rb * 256 + ((ks * 64 + l4 * 16) ^ ((rb & 7) << 4)));
    }
#pragma unroll
    for (int i = 0; i < 2; ++i)
#pragma unroll
      for (int j = 0; j < 4; ++j)
        acc[i][j] = __builtin_amdgcn_mfma_f32_16x16x32_bf16(af[i], bfv[j], acc[i][j], 0, 0, 0);
  }
  // scale by gamma^(row_in_chunk+1)
#pragma unroll
  for (int i = 0; i < 2; ++i)
#pragma unroll
    for (int r = 0; r < 4; ++r) {
      const float sc = dpw[HF * 64 + wr * 32 + i * 16 + l4 * 4 + r + 1];
#pragma unroll
      for (int j = 0; j < 4; ++j) acc[i][j][r] *= sc;
    }
  __syncthreads();
  // stage K rows (cols of QK^T): HF=0 -> 64 rows, HF=1 -> 128 rows
  if constexpr (HF == 0)
    stage_rows<64>((const char*)(Kb + ((size_t)bh * SEQ_ + c * 128) * 128), 256, lB, tid);
  else
    stage_rows<128>((const char*)(Kb + ((size_t)bh * SEQ_ + c * 128) * 128), 256, lB, tid);
  __syncthreads();

  // intra scores: Q @ K^T  (out 64 x 64*(1+HF))
  v4f sacc[2][NS];
#pragma unroll
  for (int i = 0; i < 2; ++i)
#pragma unroll
    for (int j = 0; j < NS; ++j) sacc[i][j] = v4f{0.f, 0.f, 0.f, 0.f};
#pragma unroll
  for (int ks = 0; ks < 4; ++ks) {
    v8bf af[2], bfv[NS];
#pragma unroll
    for (int i = 0; i < 2; ++i) {
      const int ra = wr * 32 + i * 16 + l15;
      af[i] = *(const v8bf*)(lA + ra * 256 + ((ks * 64 + l4 * 16) ^ ((ra & 7) << 4)));
    }
#pragma unroll
    for (int j = 0; j < NS; ++j) {
      const int rb = wc * (16 * NS) + j * 16 + l15;
      bfv[j] = *(const v8bf*)(lB + rb * 256 + ((ks * 64 + l4 * 16) ^ ((rb & 7) << 4)));
    }
#pragma unroll
    for (int i = 0; i < 2; ++i)
#pragma unroll
      for (int j = 0; j < NS; ++j)
        sacc[i][j] = __builtin_amdgcn_mfma_f32_16x16x32_bf16(af[i], bfv[j], sacc[i][j], 0, 0, 0);
  }
  __syncthreads();  // all reads of lA (Q), lB (K) done

  // decayed P (bf16) -> lA; stage V^T -> lB
#pragma unroll
  for (int i = 0; i < 2; ++i)
#pragma unroll
    for (int r = 0; r < 4; ++r) {
      const int jl = wr * 32 + i * 16 + l4 * 4 + r;
#pragma unroll
      for (int j = 0; j < NS; ++j) {
        const int icol = wc * (16 * NS) + j * 16 + l15;
        const int d = HF * 64 + jl - icol;
        const float p = (d < 0) ? 0.f : sacc[i][j][r] * dpw[d];
        *(unsigned short*)(lA + jl * 256 + ((icol * 2) ^ ((jl & 7) << 4))) = f2bf(p);
      }
    }
  if constexpr (HF == 0)
    stage_t<128>(VTb + (size_t)bh * 128 * SEQ_ + (size_t)c * 128, SEQ_, lB, tid);  // 128e x 64i (128B rows)
  else
    stage_rows<128>((const char*)(VTb + (size_t)bh * 128 * SEQ_ + (size_t)c * 128), SEQ_ * 2, lB, tid);
  __syncthreads();

  // PV: acc += P @ V  (k = i within chunk, 64*(1+HF))
#pragma unroll
  for (int ks = 0; ks < KS; ++ks) {
    v8bf af[2], bfv[4];
#pragma unroll
    for (int i = 0; i < 2; ++i) {
      const int ra = wr * 32 + i * 16 + l15;
      af[i] = *(const v8bf*)(lA + ra * 256 + ((ks * 64 + l4 * 16) ^ ((ra & 7) << 4)));
    }
#pragma unroll
    for (int j = 0; j < 4; ++j) {
      const int rb = wc * 64 + j * 16 + l15;
      if constexpr (HF == 0)
        bfv[j] = *(const v8bf*)(lB + rb * 128 + ((ks * 64 + l4 * 16) ^ ((rb & 7) << 4)));
      else
        bfv[j] = *(const v8bf*)(lB + rb * 256 + ((ks * 64 + l4 * 16) ^ ((rb & 7) << 4)));
    }
#pragma unroll
    for (int i = 0; i < 2; ++i)
#pragma unroll
      for (int j = 0; j < 4; ++j)
        acc[i][j] = __builtin_amdgcn_mfma_f32_16x16x32_bf16(af[i], bfv[j], acc[i][j], 0, 0, 0);
  }

  // group-norm partials per row
#pragma unroll
  for (int i = 0; i < 2; ++i)
#pragma unroll
    for (int r = 0; r < 4; ++r) {
      const int jl = wr * 32 + i * 16 + l4 * 4 + r;
      float s1 = 0.f, s2 = 0.f;
#pragma unroll
      for (int j = 0; j < 4; ++j) { const float v = acc[i][j][r]; s1 += v; s2 += v * v; }
#pragma unroll
      for (int o = 1; o < 16; o <<= 1) { s1 += __shfl_xor(s1, o); s2 += __shfl_xor(s2, o); }
      if (l15 == 0) { rs[(wc * 64 + jl) * 2] = s1; rs[(wc * 64 + jl) * 2 + 1] = s2; }
    }
  __syncthreads();
#pragma unroll
  for (int i = 0; i < 2; ++i)
#pragma unroll
    for (int r = 0; r < 4; ++r) {
      const int jl = wr * 32 + i * 16 + l4 * 4 + r;
      const float s1 = rs[jl * 2] + rs[(64 + jl) * 2];
      const float s2 = rs[jl * 2 + 1] + rs[(64 + jl) * 2 + 1];
      const float mu = s1 * (1.f / 128.f);
      const float var = s2 * (1.f / 128.f) - mu * mu;
      const float rstd = rsqrtf(var + 1e-5f);
      const size_t t = (size_t)(b * SEQ_ + j0 + jl);
#pragma unroll
      for (int j = 0; j < 4; ++j) {
        const int dd = wc * 64 + j * 16 + l15;
        const int cc = h * 128 + dd;
        const float g0 = bf2f(G0b[t * 512 + cc]);
        float o = (acc[i][j][r] - mu) * rstd * gnw[cc] + gnb[cc];
        o *= silu_(g0);
        Gb[t * 512 + cc] = f2bf(o);
      }
    }
}

__global__ __launch_bounds__(256) void ret3_k(
    const unsigned short* __restrict__ Qb, const unsigned short* __restrict__ Kb,
    const unsigned short* __restrict__ VTb, const unsigned short* __restrict__ Sb,
    const unsigned short* __restrict__ G0b, const float* __restrict__ gnw,
    const float* __restrict__ gnb, unsigned short* __restrict__ Gb) {
  __shared__ __align__(16) char lA[16384];
  __shared__ __align__(16) char lB[32768];
  __shared__ float dpw[132];
  __shared__ float rs[128 * 2];
  const int bh = blockIdx.x;
  const int hf = blockIdx.y & 1, c = blockIdx.y >> 1;
  const int tid = threadIdx.x;
  const int h = bh & 3;
  const float gamma = 1.f - expf(-3.4657359028f - 0.9241962407f * (float)h);
  const float l2g = log2f(gamma);
  if (tid < 132) dpw[tid] = exp2f(l2g * (float)tid);
  if (hf == 0)
    ret3_body<0>(Qb, Kb, VTb, Sb, G0b, gnw, gnb, Gb, lA, lB, dpw, rs, bh, c, tid);
  else
    ret3_body<1>(Qb, Kb, VTb, Sb, G0b, gnw, gnb, Gb, lA, lB, dpw, rs, bh, c, tid);
}

extern "C" void kernel_launch(void* const* d_in, const int* in_sizes, int n_in,
                              void* d_out, int out_size, void* d_ws, size_t ws_size,
                              hipStream_t stream) {
  const float* X = (const float*)d_in[0];
  const float* Wq = (const float*)d_in[1];
  const float* Wk = (const float*)d_in[2];
  const float* Wv = (const float*)d_in[3];
  const float* Wg = (const float*)d_in[4];
  const float* Wo = (const float*)d_in[5];
  const float* gnw = (const float*)d_in[6];
  const float* gnb = (const float*)d_in[7];
  const float* ln1w = (const float*)d_in[8];
  const float* ln1b = (const float*)d_in[9];
  const float* ln2w = (const float*)d_in[10];
  const float* ln2b = (const float*)d_in[11];
  const float* f1w = (const float*)d_in[12];
  const float* f1b = (const float*)d_in[13];
  const float* f2w = (const float*)d_in[14];
  const float* f2b = (const float*)d_in[15];

  char* ws = (char*)d_ws;
  float* TAB = (float*)(ws + 0);                            // 2 MB
  unsigned short* WTQ = (unsigned short*)(ws + 2097152);    // 8 MB  [L][2048][512]
  unsigned short* WTO = (unsigned short*)(ws + 10485760);   // 2 MB  [L][512][512]
  unsigned short* WF1 = (unsigned short*)(ws + 12582912);   // 4 MB  [L][1024][512]
  unsigned short* WF2 = (unsigned short*)(ws + 16777216);   // 4 MB  [L][512][1024]
  unsigned short* XNb = (unsigned short*)(ws + 20971520);   // 4 MB
  unsigned short* Qb  = (unsigned short*)(ws + 25165824);   // 4 MB
  unsigned short* Kb  = (unsigned short*)(ws + 29360128);   // 4 MB
  unsigned short* KTw = (unsigned short*)(ws + 33554432);   // 4 MB
  unsigned short* VTb = (unsigned short*)(ws + 37748736);   // 4 MB
  unsigned short* G0b = (unsigned short*)(ws + 46137344);   // 4 MB
  unsigned short* Sbf = (unsigned short*)(ws + 50331648);   // 4 MB
  unsigned short* Gb  = (unsigned short*)(ws + 54525952);   // 4 MB
  float* Y   = (float*)(ws + 58720256);                     // 8 MB
  float* XB  = (float*)(ws + 67108864);                     // 8 MB
  unsigned short* F1b = (unsigned short*)(ws + 75497472);   // 8 MB
  float* qc = TAB, * qs = TAB + 131072, * kc = TAB + 262144, * ks = TAB + 393216;

  setup_k<<<2816, 256, 0, stream>>>(Wq, Wk, Wv, Wg, Wo, f1w, f2w, TAB, WTQ, WTO, WF1, WF2);

  const float* Xcur = X;
  for (int l = 0; l < 4; ++l) {
    ln_bf_k<<<1024, 256, 0, stream>>>(Xcur, ln1w + l * 512, ln1b + l * 512, XNb);
    mm_k<128, 128, 0><<<dim3(32, 16), 256, 0, stream>>>(
        XNb, WTQ + (size_t)l * 2048 * 512, 512, qc, qs, kc, ks,
        Qb, Kb, KTw, VTb, G0b, nullptr, nullptr, nullptr, nullptr);
    ret12_k<<<dim3(8, 4), 256, 0, stream>>>(VTb, KTw, Sbf);
    ret3_k<<<dim3(8, 32), 256, 0, stream>>>(Qb, Kb, VTb, Sbf, G0b,
                                            gnw + l * 512, gnb + l * 512, Gb);
    mm_k<128, 64, 1><<<dim3(32, 8), 256, 0, stream>>>(
        Gb, WTO + (size_t)l * 512 * 512, 512, nullptr, nullptr, nullptr, nullptr,
        nullptr, nullptr, nullptr, nullptr, nullptr, Xcur, nullptr, Y, nullptr);
    ln_bf_k<<<1024, 256, 0, stream>>>(Y, ln2w + l * 512, ln2b + l * 512, XNb);
    mm_k<128, 128, 2><<<dim3(32, 8), 256, 0, stream>>>(
        XNb, WF1 + (size_t)l * 1024 * 512, 512, nullptr, nullptr, nullptr, nullptr,
        nullptr, nullptr, nullptr, nullptr, nullptr, f1b + l * 1024, nullptr, nullptr, F1b);
    float* outX = (l == 3) ? (float*)d_out : XB;
    mm_k<128, 64, 3><<<dim3(32, 8), 256, 0, stream>>>(
        F1b, WF2 + (size_t)l * 512 * 1024, 1024, nullptr, nullptr, nullptr, nullptr,
        nullptr, nullptr, nullptr, nullptr, nullptr, f2b + l * 512, Y, outX, nullptr);
    Xcur = XB;
  }
}

// Round 8
// 503.199 us; speedup vs baseline: 1.0997x; 1.0997x over previous
//
#include <hip/hip_runtime.h>
#include <hip/hip_bf16.h>
#include <cstdint>
#include <cstddef>

#define SEQ_ 2048

typedef __bf16 v8bf __attribute__((ext_vector_type(8)));
typedef float v4f __attribute__((ext_vector_type(4)));

__device__ __forceinline__ unsigned short f2bf(float f) {
  unsigned u = __float_as_uint(f);
  return (unsigned short)((u + 0x7FFFu + ((u >> 16) & 1u)) >> 16);
}
__device__ __forceinline__ float bf2f(unsigned short h) {
  return __uint_as_float(((unsigned)h) << 16);
}
__device__ __forceinline__ float silu_(float x) { return x / (1.f + expf(-x)); }
__device__ __forceinline__ float gelu_(float x) { return 0.5f * x * (1.f + erff(x * 0.70710678118654752f)); }

__device__ __forceinline__ void gl_lds16(const void* g, void* l) {
  __builtin_amdgcn_global_load_lds((const __attribute__((address_space(1))) void*)g,
                                   (__attribute__((address_space(3))) void*)l, 16, 0, 0);
}

// stage ROWS x 64 bf16 (128B rows), source row stride ldk elements, XOR-swizzled
template <int ROWS>
__device__ __forceinline__ void stage_t(const unsigned short* gsrc, int ldk, char* lds, int tid) {
  const int wid = tid >> 6;
#pragma unroll
  for (int p = 0; p < ROWS / 32; ++p) {
    const int L = p * 256 + tid;
    const int row = L >> 3, slot = L & 7;
    gl_lds16((const char*)(gsrc + (size_t)row * ldk) + ((slot * 16) ^ ((row & 7) << 4)),
             lds + (p * 256 + wid * 64) * 16);
  }
}

// stage NROWS x 256B rows (row byte-stride srow), XOR-swizzled
template <int NROWS>
__device__ __forceinline__ void stage_rows(const char* gbase, int srow, char* lds, int tid) {
  const int wid = tid >> 6;
#pragma unroll
  for (int q = 0; q < NROWS / 16; ++q) {
    const int L = q * 256 + tid;
    const int row = L >> 4;
    const int slot = L & 15;
    gl_lds16(gbase + (size_t)row * srow + ((slot * 16) ^ ((row & 7) << 4)),
             lds + (q * 256 + wid * 64) * 16);
  }
}

// ---------------- fused setup: xpos tables + coalesced tiled weight transposes ----------------
__global__ __launch_bounds__(256) void setup_k(const float* __restrict__ Wq, const float* __restrict__ Wk,
                                               const float* __restrict__ Wv, const float* __restrict__ Wg,
                                               const float* __restrict__ Wo, const float* __restrict__ f1w,
                                               const float* __restrict__ f2w, float* __restrict__ tab,
                                               unsigned short* __restrict__ WTQ, unsigned short* __restrict__ WTO,
                                               unsigned short* __restrict__ WF1, unsigned short* __restrict__ WF2) {
  const int b = blockIdx.x, tid = threadIdx.x;
  if (b < 512) {
    const int idx = b * 256 + tid;
    const int pos = idx >> 6, i = idx & 63;
    const float si = (2.f * (float)i + 51.2f) * (1.f / 179.2f);
    const float sc = powf(si, (float)pos * (1.f / 512.f));
    const float invf = powf(10000.f, -(float)i * (1.f / 64.f));
    const float ang = (float)pos * invf;
    const float cs = cosf(ang), sn = sinf(ang);
    tab[idx] = cs * sc;
    tab[131072 + idx] = sn * sc;
    tab[262144 + idx] = cs / sc;
    tab[393216 + idx] = sn / sc;
    return;
  }
  __shared__ float t[64][65];
  const float* src;
  unsigned short* dst;
  int ldn, ldk;
  int b2 = b - 512;
  if (b2 < 768) {  // Q/K/V: [l][h][512][128] -> WTQ [l][sec*512+h*128+e][512]
    const int l = b2 / 192, r = b2 % 192, sec = r / 64, r2 = r % 64, h = r2 >> 4, tt = r2 & 15;
    const int kt = tt >> 1, et = tt & 1;
    const float* W = (sec == 0) ? Wq : (sec == 1) ? Wk : Wv;
    src = W + (((size_t)(l * 4 + h) * 512 + kt * 64) * 128 + et * 64);
    ldn = 128;
    dst = WTQ + (size_t)l * 1048576 + (size_t)(sec * 512 + h * 128 + et * 64) * 512 + kt * 64;
    ldk = 512;
  } else if (b2 < 1024) {  // Wg: [l][512][512] -> WTQ cols 1536..2047
    b2 -= 768;
    const int l = b2 >> 6, tt = b2 & 63, kt = tt >> 3, nt = tt & 7;
    src = Wg + (size_t)l * 262144 + (size_t)kt * 64 * 512 + nt * 64;
    ldn = 512;
    dst = WTQ + (size_t)l * 1048576 + (size_t)(1536 + nt * 64) * 512 + kt * 64;
    ldk = 512;
  } else if (b2 < 1280) {  // Wo
    b2 -= 1024;
    const int l = b2 >> 6, tt = b2 & 63, kt = tt >> 3, nt = tt & 7;
    src = Wo + (size_t)l * 262144 + (size_t)kt * 64 * 512 + nt * 64;
    ldn = 512;
    dst = WTO + (size_t)l * 262144 + (size_t)nt * 64 * 512 + kt * 64;
    ldk = 512;
  } else if (b2 < 1792) {  // f1: [l][512][1024] -> [l][1024][512]
    b2 -= 1280;
    const int l = b2 >> 7, tt = b2 & 127, kt = tt >> 4, nt = tt & 15;
    src = f1w + (size_t)l * 524288 + (size_t)kt * 64 * 1024 + nt * 64;
    ldn = 1024;
    dst = WF1 + (size_t)l * 524288 + (size_t)nt * 64 * 512 + kt * 64;
    ldk = 512;
  } else {  // f2: [l][1024][512] -> [l][512][1024]
    b2 -= 1792;
    const int l = b2 >> 7, tt = b2 & 127, kt = tt >> 3, nt = tt & 7;
    src = f2w + (size_t)l * 524288 + (size_t)kt * 64 * 512 + nt * 64;
    ldn = 512;
    dst = WF2 + (size_t)l * 524288 + (size_t)nt * 64 * 1024 + kt * 64;
    ldk = 1024;
  }
#pragma unroll
  for (int p = 0; p < 4; ++p) {
    const int idx = p * 256 + tid;
    const int kr = idx >> 4, c4 = (idx & 15) * 4;
    const float4 v = *(const float4*)(src + (size_t)kr * ldn + c4);
    t[kr][c4] = v.x; t[kr][c4 + 1] = v.y; t[kr][c4 + 2] = v.z; t[kr][c4 + 3] = v.w;
  }
  __syncthreads();
#pragma unroll
  for (int p = 0; p < 2; ++p) {
    const int idx = p * 256 + tid;
    const int nr = idx >> 3, k8 = (idx & 7) * 8;
    unsigned short o[8];
#pragma unroll
    for (int j = 0; j < 8; ++j) o[j] = f2bf(t[k8 + j][nr]);
    uint4 pk;
    pk.x = o[0] | ((unsigned)o[1] << 16);
    pk.y = o[2] | ((unsigned)o[3] << 16);
    pk.z = o[4] | ((unsigned)o[5] << 16);
    pk.w = o[6] | ((unsigned)o[7] << 16);
    *(uint4*)(dst + (size_t)nr * ldk + k8) = pk;
  }
}

// ---------------- LayerNorm (fp32 in, bf16 out) ----------------
__global__ __launch_bounds__(256) void ln_bf_k(const float* __restrict__ x, const float* __restrict__ w,
                                               const float* __restrict__ bv, unsigned short* __restrict__ out) {
  const int row = blockIdx.x * 4 + (threadIdx.x >> 6);
  const int lane = threadIdx.x & 63;
  const float* xr = x + (size_t)row * 512 + lane * 8;
  const float4 v0 = *(const float4*)xr;
  const float4 v1 = *(const float4*)(xr + 4);
  float va[8] = {v0.x, v0.y, v0.z, v0.w, v1.x, v1.y, v1.z, v1.w};
  float s = 0.f, ss = 0.f;
#pragma unroll
  for (int j = 0; j < 8; ++j) { s += va[j]; ss += va[j] * va[j]; }
#pragma unroll
  for (int o = 1; o < 64; o <<= 1) { s += __shfl_xor(s, o); ss += __shfl_xor(ss, o); }
  const float mu = s * (1.f / 512.f);
  const float var = ss * (1.f / 512.f) - mu * mu;
  const float rstd = rsqrtf(var + 1e-5f);
  const int c = lane * 8;
  unsigned short o16[8];
#pragma unroll
  for (int j = 0; j < 8; ++j) o16[j] = f2bf((va[j] - mu) * rstd * w[c + j] + bv[c + j]);
  uint4 pk;
  pk.x = o16[0] | ((unsigned)o16[1] << 16);
  pk.y = o16[2] | ((unsigned)o16[3] << 16);
  pk.z = o16[4] | ((unsigned)o16[5] << 16);
  pk.w = o16[6] | ((unsigned)o16[7] << 16);
  *(uint4*)(out + (size_t)row * 512 + c) = pk;
}

// ---------------- bf16 MFMA GEMM: BK=64, double-buffered 1-deep prefetch ----------------
template <int BM, int BN, int EPI>
__global__ __launch_bounds__(256) void mm_k(
    const unsigned short* __restrict__ A, const unsigned short* __restrict__ Bt, const int K,
    const float* __restrict__ t_qc, const float* __restrict__ t_qs,
    const float* __restrict__ t_kc, const float* __restrict__ t_ks,
    unsigned short* __restrict__ o_q, unsigned short* __restrict__ o_k,
    unsigned short* __restrict__ o_ktw, unsigned short* __restrict__ o_vt,
    unsigned short* __restrict__ o_g0,
    const float* __restrict__ auxf, const float* __restrict__ auxf2,
    float* __restrict__ o_f32, unsigned short* __restrict__ o_bf16) {
  constexpr int MR = BM / 32, NR = BN / 32;
  constexpr int BMB = BM * 128, BNB = BN * 128;
  __shared__ __align__(16) char smem[2 * (BMB + BNB)];
  const int tid = threadIdx.x, lane = tid & 63, wid = tid >> 6;
  const int wr = wid >> 1, wc = wid & 1;
  const int l15 = lane & 15, l4 = lane >> 4;
  const int m0 = blockIdx.x * BM, n0 = blockIdx.y * BN;
  const int N = gridDim.y * BN;
  v4f acc[MR][NR];
#pragma unroll
  for (int i = 0; i < MR; ++i)
#pragma unroll
    for (int j = 0; j < NR; ++j) acc[i][j] = v4f{0.f, 0.f, 0.f, 0.f};

  const unsigned short* Ab = A + (size_t)m0 * K;
  const unsigned short* Bb = Bt + (size_t)n0 * K;
  const int NT = K >> 6;
  int cur = 0;
  stage_t<BM>(Ab, K, smem, tid);
  stage_t<BN>(Bb, K, smem + 2 * BMB, tid);
  __syncthreads();
  for (int t = 0; t < NT; ++t) {
    if (t + 1 < NT) {
      stage_t<BM>(Ab + (t + 1) * 64, K, smem + (cur ^ 1) * BMB, tid);
      stage_t<BN>(Bb + (t + 1) * 64, K, smem + 2 * BMB + (cur ^ 1) * BNB, tid);
    }
    const char* Ac = smem + cur * BMB;
    const char* Bc = smem + 2 * BMB + cur * BNB;
#pragma unroll
    for (int ks = 0; ks < 2; ++ks) {
      v8bf af[MR], bfv[NR];
#pragma unroll
      for (int i = 0; i < MR; ++i) {
        const int row = wr * (BM / 2) + i * 16 + l15;
        af[i] = *(const v8bf*)(Ac + row * 128 + ((ks * 64 + l4 * 16) ^ ((row & 7) << 4)));
      }
#pragma unroll
      for (int j = 0; j < NR; ++j) {
        const int row = wc * (BN / 2) + j * 16 + l15;
        bfv[j] = *(const v8bf*)(Bc + row * 128 + ((ks * 64 + l4 * 16) ^ ((row & 7) << 4)));
      }
#pragma unroll
      for (int i = 0; i < MR; ++i)
#pragma unroll
        for (int j = 0; j < NR; ++j)
          acc[i][j] = __builtin_amdgcn_mfma_f32_16x16x32_bf16(af[i], bfv[j], acc[i][j], 0, 0, 0);
    }
    __syncthreads();
    cur ^= 1;
  }

  // ---- epilogue ----
  if constexpr (EPI == 0) {
    const int sec = n0 >> 9;
    const int h = (n0 >> 7) & 3;
    const int srow0 = m0 & (SEQ_ - 1);
    const int bh = ((m0 >> 11) << 2) | h;
    unsigned short* sT = (unsigned short*)smem;  // [128 e][136]
    const float gamma = 1.f - expf(-3.4657359028f - 0.9241962407f * (float)h);
    const float l2g = log2f(gamma);
#pragma unroll
    for (int i = 0; i < MR; ++i) {
#pragma unroll
      for (int r = 0; r < 4; ++r) {
        const int rl = wr * (BM / 2) + i * 16 + l4 * 4 + r;
        const int srow = srow0 + rl;
        const float wk = (sec == 1) ? exp2f(l2g * (float)(127 - (rl & 127))) : 0.f;
#pragma unroll
        for (int j = 0; j < NR; ++j) {
          const int cl = wc * (BN / 2) + j * 16 + l15;
          float v = acc[i][j][r];
          if (sec <= 1) {
            const float p = __shfl_xor(v, 1);
            const float* ct = (sec == 0) ? t_qc : t_kc;
            const float* st = (sec == 0) ? t_qs : t_ks;
            const float c_ = ct[srow * 64 + (cl >> 1)];
            const float s_ = st[srow * 64 + (cl >> 1)];
            const float o = (lane & 1) ? fmaf(v, c_, p * s_) : fmaf(v, c_, -p * s_);
            if (sec == 0) {
              o_q[((size_t)bh * SEQ_ + srow) * 128 + cl] = f2bf(o);
            } else {
              o_k[((size_t)bh * SEQ_ + srow) * 128 + cl] = f2bf(o);
              sT[cl * 136 + rl] = f2bf(o * wk);
            }
          } else if (sec == 2) {
            sT[cl * 136 + rl] = f2bf(v);
          } else {
            o_g0[(size_t)(m0 + rl) * 512 + cl] = f2bf(v);
          }
        }
      }
    }
    if (sec == 1 || sec == 2) {
      __syncthreads();
      unsigned short* dstT = ((sec == 1) ? o_ktw : o_vt) + (size_t)bh * 128 * SEQ_ + srow0;
#pragma unroll
      for (int u = 0; u < 8; ++u) {
        const int idx = u * 256 + tid;
        const int d = idx >> 4, j8 = idx & 15;
        *(v8bf*)(dstT + (size_t)d * SEQ_ + j8 * 8) = *(const v8bf*)(sT + d * 136 + j8 * 8);
      }
    }
  } else {
#pragma unroll
    for (int i = 0; i < MR; ++i) {
#pragma unroll
      for (int r = 0; r < 4; ++r) {
        const int row = m0 + wr * (BM / 2) + i * 16 + l4 * 4 + r;
#pragma unroll
        for (int j = 0; j < NR; ++j) {
          const int col = n0 + wc * (BN / 2) + j * 16 + l15;
          const float v = acc[i][j][r];
          if constexpr (EPI == 1) {
            o_f32[(size_t)row * 512 + col] = v + auxf[(size_t)row * 512 + col];
          } else if constexpr (EPI == 2) {
            o_bf16[(size_t)row * N + col] = f2bf(gelu_(v + auxf[col]));
          } else {
            o_f32[(size_t)row * 512 + col] = v + auxf[col] + auxf2[(size_t)row * 512 + col];
          }
        }
      }
    }
  }
}

// ---------------- retention phase 1: chunk summaries U[eo][d] ----------------
__global__ __launch_bounds__(256) void ret1_k(const unsigned short* __restrict__ VT,
                                              const unsigned short* __restrict__ KTw,
                                              float* __restrict__ U) {
  __shared__ __align__(16) char lA[32768];
  __shared__ __align__(16) char lB[32768];
  const int bh = blockIdx.x, c = blockIdx.y;
  const int tid = threadIdx.x, lane = tid & 63, wid = tid >> 6;
  const int wr = wid >> 1, wc = wid & 1;
  const int l15 = lane & 15, l4 = lane >> 4;
  stage_rows<128>((const char*)(VT + (size_t)bh * 128 * SEQ_ + (size_t)c * 128), SEQ_ * 2, lA, tid);
  stage_rows<128>((const char*)(KTw + (size_t)bh * 128 * SEQ_ + (size_t)c * 128), SEQ_ * 2, lB, tid);
  __syncthreads();
  v4f acc[4][4];
#pragma unroll
  for (int i = 0; i < 4; ++i)
#pragma unroll
    for (int j = 0; j < 4; ++j) acc[i][j] = v4f{0.f, 0.f, 0.f, 0.f};
#pragma unroll
  for (int ks = 0; ks < 4; ++ks) {
    v8bf af[4], bfv[4];
#pragma unroll
    for (int i = 0; i < 4; ++i) {
      const int ra = wr * 64 + i * 16 + l15;
      af[i] = *(const v8bf*)(lA + ra * 256 + ((ks * 64 + l4 * 16) ^ ((ra & 7) << 4)));
      const int rb = wc * 64 + i * 16 + l15;
      bfv[i] = *(const v8bf*)(lB + rb * 256 + ((ks * 64 + l4 * 16) ^ ((rb & 7) << 4)));
    }
#pragma unroll
    for (int i = 0; i < 4; ++i)
#pragma unroll
      for (int j = 0; j < 4; ++j)
        acc[i][j] = __builtin_amdgcn_mfma_f32_16x16x32_bf16(af[i], bfv[j], acc[i][j], 0, 0, 0);
  }
  float* ub = U + ((size_t)bh * 16 + c) * 16384;
#pragma unroll
  for (int i = 0; i < 4; ++i)
#pragma unroll
    for (int r = 0; r < 4; ++r) {
      const int rd = wr * 64 + i * 16 + l4 * 4 + r;
#pragma unroll
      for (int j = 0; j < 4; ++j) {
        const int ce = wc * 64 + j * 16 + l15;
        ub[rd * 128 + ce] = acc[i][j][r];
      }
    }
}

// ---------------- retention phase 2: sequential state scan ----------------
__global__ __launch_bounds__(256) void ret2_k(const float* __restrict__ U, unsigned short* __restrict__ Sb) {
  const int bh = blockIdx.x;
  const int idx = blockIdx.y * 256 + threadIdx.x;  // 0..16383
  const int h = bh & 3;
  const float gamma = 1.f - expf(-3.4657359028f - 0.9241962407f * (float)h);
  const float g128 = exp2f(log2f(gamma) * 128.f);
  float s = 0.f;
#pragma unroll
  for (int c = 0; c < 16; ++c) {
    Sb[((size_t)bh * 16 + c) * 16384 + idx] = f2bf(s);
    s = s * g128 + U[((size_t)bh * 16 + c) * 16384 + idx];
  }
}

// ---------------- retention phase 3: half-chunk blocks, output + groupnorm + gate ----------------
template <int HF>
__device__ __forceinline__ void ret3_body(
    const unsigned short* Qb, const unsigned short* Kb, const unsigned short* VTb,
    const unsigned short* Sb, const unsigned short* G0b, const float* gnw,
    const float* gnb, unsigned short* Gb, char* lA, char* lB, const float* dpw,
    float* rs, int bh, int c, int tid) {
  const int h = bh & 3, b = bh >> 2;
  const int lane = tid & 63, wid = tid >> 6;
  const int wr = wid >> 1, wc = wid & 1;
  const int l15 = lane & 15, l4 = lane >> 4;
  constexpr int NS = 2 + 2 * HF;     // QK col frags per wave
  constexpr int KS = 2 + 2 * HF;     // PV k-steps
  const int j0 = c * 128 + HF * 64;  // global chunk-row base

  // stage Q (64x256B) -> lA, S (128x256B) -> lB
  stage_rows<64>((const char*)(Qb + ((size_t)bh * SEQ_ + j0) * 128), 256, lA, tid);
  stage_rows<128>((const char*)(Sb + ((size_t)bh * 16 + c) * 16384), 256, lB, tid);
  __syncthreads();

  // inter-chunk: O = Q @ S_before  (out 64 x 128)
  v4f acc[2][4];
#pragma unroll
  for (int i = 0; i < 2; ++i)
#pragma unroll
    for (int j = 0; j < 4; ++j) acc[i][j] = v4f{0.f, 0.f, 0.f, 0.f};
#pragma unroll
  for (int ks = 0; ks < 4; ++ks) {
    v8bf af[2], bfv[4];
#pragma unroll
    for (int i = 0; i < 2; ++i) {
      const int ra = wr * 32 + i * 16 + l15;
      af[i] = *(const v8bf*)(lA + ra * 256 + ((ks * 64 + l4 * 16) ^ ((ra & 7) << 4)));
    }
#pragma unroll
    for (int j = 0; j < 4; ++j) {
      const int rb = wc * 64 + j * 16 + l15;
      bfv[j] = *(const v8bf*)(lB + rb * 256 + ((ks * 64 + l4 * 16) ^ ((rb & 7) << 4)));
    }
#pragma unroll
    for (int i = 0; i < 2; ++i)
#pragma unroll
      for (int j = 0; j < 4; ++j)
        acc[i][j] = __builtin_amdgcn_mfma_f32_16x16x32_bf16(af[i], bfv[j], acc[i][j], 0, 0, 0);
  }
  // scale by gamma^(row_in_chunk+1)
#pragma unroll
  for (int i = 0; i < 2; ++i)
#pragma unroll
    for (int r = 0; r < 4; ++r) {
      const float sc = dpw[HF * 64 + wr * 32 + i * 16 + l4 * 4 + r + 1];
#pragma unroll
      for (int j = 0; j < 4; ++j) acc[i][j][r] *= sc;
    }
  __syncthreads();
  // stage K rows (cols of QK^T): HF=0 -> 64 rows, HF=1 -> 128 rows
  if constexpr (HF == 0)
    stage_rows<64>((const char*)(Kb + ((size_t)bh * SEQ_ + c * 128) * 128), 256, lB, tid);
  else
    stage_rows<128>((const char*)(Kb + ((size_t)bh * SEQ_ + c * 128) * 128), 256, lB, tid);
  __syncthreads();

  // intra scores: Q @ K^T  (out 64 x 64*(1+HF))
  v4f sacc[2][NS];
#pragma unroll
  for (int i = 0; i < 2; ++i)
#pragma unroll
    for (int j = 0; j < NS; ++j) sacc[i][j] = v4f{0.f, 0.f, 0.f, 0.f};
#pragma unroll
  for (int ks = 0; ks < 4; ++ks) {
    v8bf af[2], bfv[NS];
#pragma unroll
    for (int i = 0; i < 2; ++i) {
      const int ra = wr * 32 + i * 16 + l15;
      af[i] = *(const v8bf*)(lA + ra * 256 + ((ks * 64 + l4 * 16) ^ ((ra & 7) << 4)));
    }
#pragma unroll
    for (int j = 0; j < NS; ++j) {
      const int rb = wc * (16 * NS) + j * 16 + l15;
      bfv[j] = *(const v8bf*)(lB + rb * 256 + ((ks * 64 + l4 * 16) ^ ((rb & 7) << 4)));
    }
#pragma unroll
    for (int i = 0; i < 2; ++i)
#pragma unroll
      for (int j = 0; j < NS; ++j)
        sacc[i][j] = __builtin_amdgcn_mfma_f32_16x16x32_bf16(af[i], bfv[j], sacc[i][j], 0, 0, 0);
  }
  __syncthreads();  // all reads of lA (Q), lB (K) done

  // decayed P (bf16) -> lA; stage V^T -> lB
#pragma unroll
  for (int i = 0; i < 2; ++i)
#pragma unroll
    for (int r = 0; r < 4; ++r) {
      const int jl = wr * 32 + i * 16 + l4 * 4 + r;
#pragma unroll
      for (int j = 0; j < NS; ++j) {
        const int icol = wc * (16 * NS) + j * 16 + l15;
        const int d = HF * 64 + jl - icol;
        const float p = (d < 0) ? 0.f : sacc[i][j][r] * dpw[d];
        *(unsigned short*)(lA + jl * 256 + ((icol * 2) ^ ((jl & 7) << 4))) = f2bf(p);
      }
    }
  if constexpr (HF == 0)
    stage_t<128>(VTb + (size_t)bh * 128 * SEQ_ + (size_t)c * 128, SEQ_, lB, tid);  // 128e x 64i (128B rows)
  else
    stage_rows<128>((const char*)(VTb + (size_t)bh * 128 * SEQ_ + (size_t)c * 128), SEQ_ * 2, lB, tid);
  __syncthreads();

  // PV: acc += P @ V  (k = i within chunk, 64*(1+HF))
#pragma unroll
  for (int ks = 0; ks < KS; ++ks) {
    v8bf af[2], bfv[4];
#pragma unroll
    for (int i = 0; i < 2; ++i) {
      const int ra = wr * 32 + i * 16 + l15;
      af[i] = *(const v8bf*)(lA + ra * 256 + ((ks * 64 + l4 * 16) ^ ((ra & 7) << 4)));
    }
#pragma unroll
    for (int j = 0; j < 4; ++j) {
      const int rb = wc * 64 + j * 16 + l15;
      if constexpr (HF == 0)
        bfv[j] = *(const v8bf*)(lB + rb * 128 + ((ks * 64 + l4 * 16) ^ ((rb & 7) << 4)));
      else
        bfv[j] = *(const v8bf*)(lB + rb * 256 + ((ks * 64 + l4 * 16) ^ ((rb & 7) << 4)));
    }
#pragma unroll
    for (int i = 0; i < 2; ++i)
#pragma unroll
      for (int j = 0; j < 4; ++j)
        acc[i][j] = __builtin_amdgcn_mfma_f32_16x16x32_bf16(af[i], bfv[j], acc[i][j], 0, 0, 0);
  }

  // group-norm partials per row
#pragma unroll
  for (int i = 0; i < 2; ++i)
#pragma unroll
    for (int r = 0; r < 4; ++r) {
      const int jl = wr * 32 + i * 16 + l4 * 4 + r;
      float s1 = 0.f, s2 = 0.f;
#pragma unroll
      for (int j = 0; j < 4; ++j) { const float v = acc[i][j][r]; s1 += v; s2 += v * v; }
#pragma unroll
      for (int o = 1; o < 16; o <<= 1) { s1 += __shfl_xor(s1, o); s2 += __shfl_xor(s2, o); }
      if (l15 == 0) { rs[(wc * 64 + jl) * 2] = s1; rs[(wc * 64 + jl) * 2 + 1] = s2; }
    }
  __syncthreads();
#pragma unroll
  for (int i = 0; i < 2; ++i)
#pragma unroll
    for (int r = 0; r < 4; ++r) {
      const int jl = wr * 32 + i * 16 + l4 * 4 + r;
      const float s1 = rs[jl * 2] + rs[(64 + jl) * 2];
      const float s2 = rs[jl * 2 + 1] + rs[(64 + jl) * 2 + 1];
      const float mu = s1 * (1.f / 128.f);
      const float var = s2 * (1.f / 128.f) - mu * mu;
      const float rstd = rsqrtf(var + 1e-5f);
      const size_t t = (size_t)(b * SEQ_ + j0 + jl);
#pragma unroll
      for (int j = 0; j < 4; ++j) {
        const int dd = wc * 64 + j * 16 + l15;
        const int cc = h * 128 + dd;
        const float g0 = bf2f(G0b[t * 512 + cc]);
        float o = (acc[i][j][r] - mu) * rstd * gnw[cc] + gnb[cc];
        o *= silu_(g0);
        Gb[t * 512 + cc] = f2bf(o);
      }
    }
}

__global__ __launch_bounds__(256) void ret3_k(
    const unsigned short* __restrict__ Qb, const unsigned short* __restrict__ Kb,
    const unsigned short* __restrict__ VTb, const unsigned short* __restrict__ Sb,
    const unsigned short* __restrict__ G0b, const float* __restrict__ gnw,
    const float* __restrict__ gnb, unsigned short* __restrict__ Gb) {
  __shared__ __align__(16) char lA[16384];
  __shared__ __align__(16) char lB[32768];
  __shared__ float dpw[132];
  __shared__ float rs[128 * 2];
  const int bh = blockIdx.x;
  const int hf = blockIdx.y & 1, c = blockIdx.y >> 1;
  const int tid = threadIdx.x;
  const int h = bh & 3;
  const float gamma = 1.f - expf(-3.4657359028f - 0.9241962407f * (float)h);
  const float l2g = log2f(gamma);
  if (tid < 132) dpw[tid] = exp2f(l2g * (float)tid);
  if (hf == 0)
    ret3_body<0>(Qb, Kb, VTb, Sb, G0b, gnw, gnb, Gb, lA, lB, dpw, rs, bh, c, tid);
  else
    ret3_body<1>(Qb, Kb, VTb, Sb, G0b, gnw, gnb, Gb, lA, lB, dpw, rs, bh, c, tid);
}

extern "C" void kernel_launch(void* const* d_in, const int* in_sizes, int n_in,
                              void* d_out, int out_size, void* d_ws, size_t ws_size,
                              hipStream_t stream) {
  const float* X = (const float*)d_in[0];
  const float* Wq = (const float*)d_in[1];
  const float* Wk = (const float*)d_in[2];
  const float* Wv = (const float*)d_in[3];
  const float* Wg = (const float*)d_in[4];
  const float* Wo = (const float*)d_in[5];
  const float* gnw = (const float*)d_in[6];
  const float* gnb = (const float*)d_in[7];
  const float* ln1w = (const float*)d_in[8];
  const float* ln1b = (const float*)d_in[9];
  const float* ln2w = (const float*)d_in[10];
  const float* ln2b = (const float*)d_in[11];
  const float* f1w = (const float*)d_in[12];
  const float* f1b = (const float*)d_in[13];
  const float* f2w = (const float*)d_in[14];
  const float* f2b = (const float*)d_in[15];

  char* ws = (char*)d_ws;
  float* TAB = (float*)(ws + 0);                            // 2 MB
  unsigned short* WTQ = (unsigned short*)(ws + 2097152);    // 8 MB  [L][2048][512]
  unsigned short* WTO = (unsigned short*)(ws + 10485760);   // 2 MB  [L][512][512]
  unsigned short* WF1 = (unsigned short*)(ws + 12582912);   // 4 MB  [L][1024][512]
  unsigned short* WF2 = (unsigned short*)(ws + 16777216);   // 4 MB  [L][512][1024]
  unsigned short* XNb = (unsigned short*)(ws + 20971520);   // 4 MB
  unsigned short* Qb  = (unsigned short*)(ws + 25165824);   // 4 MB
  unsigned short* Kb  = (unsigned short*)(ws + 29360128);   // 4 MB
  unsigned short* KTw = (unsigned short*)(ws + 33554432);   // 4 MB
  unsigned short* VTb = (unsigned short*)(ws + 37748736);   // 4 MB
  unsigned short* G0b = (unsigned short*)(ws + 46137344);   // 4 MB
  unsigned short* Sbf = (unsigned short*)(ws + 50331648);   // 4 MB
  unsigned short* Gb  = (unsigned short*)(ws + 54525952);   // 4 MB
  float* Y   = (float*)(ws + 58720256);                     // 8 MB
  float* XB  = (float*)(ws + 67108864);                     // 8 MB
  unsigned short* F1b = (unsigned short*)(ws + 75497472);   // 8 MB (aliases U)
  float* U = (float*)(ws + 75497472);                       // 8 MB fp32
  float* qc = TAB, * qs = TAB + 131072, * kc = TAB + 262144, * ks = TAB + 393216;

  setup_k<<<2816, 256, 0, stream>>>(Wq, Wk, Wv, Wg, Wo, f1w, f2w, TAB, WTQ, WTO, WF1, WF2);

  const float* Xcur = X;
  for (int l = 0; l < 4; ++l) {
    ln_bf_k<<<1024, 256, 0, stream>>>(Xcur, ln1w + l * 512, ln1b + l * 512, XNb);
    mm_k<128, 128, 0><<<dim3(32, 16), 256, 0, stream>>>(
        XNb, WTQ + (size_t)l * 2048 * 512, 512, qc, qs, kc, ks,
        Qb, Kb, KTw, VTb, G0b, nullptr, nullptr, nullptr, nullptr);
    ret1_k<<<dim3(8, 16), 256, 0, stream>>>(VTb, KTw, U);
    ret2_k<<<dim3(8, 64), 256, 0, stream>>>(U, Sbf);
    ret3_k<<<dim3(8, 32), 256, 0, stream>>>(Qb, Kb, VTb, Sbf, G0b,
                                            gnw + l * 512, gnb + l * 512, Gb);
    mm_k<128, 64, 1><<<dim3(32, 8), 256, 0, stream>>>(
        Gb, WTO + (size_t)l * 512 * 512, 512, nullptr, nullptr, nullptr, nullptr,
        nullptr, nullptr, nullptr, nullptr, nullptr, Xcur, nullptr, Y, nullptr);
    ln_bf_k<<<1024, 256, 0, stream>>>(Y, ln2w + l * 512, ln2b + l * 512, XNb);
    mm_k<128, 128, 2><<<dim3(32, 8), 256, 0, stream>>>(
        XNb, WF1 + (size_t)l * 1024 * 512, 512, nullptr, nullptr, nullptr, nullptr,
        nullptr, nullptr, nullptr, nullptr, nullptr, f1b + l * 1024, nullptr, nullptr, F1b);
    float* outX = (l == 3) ? (float*)d_out : XB;
    mm_k<128, 64, 3><<<dim3(32, 8), 256, 0, stream>>>(
        F1b, WF2 + (size_t)l * 512 * 1024, 1024, nullptr, nullptr, nullptr, nullptr,
        nullptr, nullptr, nullptr, nullptr, nullptr, f2b + l * 512, Y, outX, nullptr);
    Xcur = XB;
  }
}